// Round 7
// baseline (34.212 us; speedup 1.0000x reference)
//
#include <hip/hip_runtime.h>
#include <math.h>

#define F_DIM 64
#define G_DIM 64
#define PTS 256   // threads per block == points per block
#define GPB 8     // gaussians per block
#define LOG2PI 1.8378770664093453f

// ---------------------------------------------------------------------------
// Single fused kernel, fully block-local (no workspace, no grid sync).
// Block b: points pb = (b>>3)*256..+256, gaussians g0 = (b&7)*8..+8.
// Per block:
//   1. Scan its 8 covariance matrices (coalesced, L2-resident): capture diag,
//      detect any nonzero off-diagonal.
//   2. Diag gaussians: closed-form coefficients rs=1/sqrt(d), m=c*rs,
//      k=sum log d + F log 2pi   (computed by wave 0 into LDS).
//   3. Non-diag gaussians: block-local Cholesky + triangular inverse in LDS
//      (fallback, correctness only).
//   4. maha + exp, thread-per-point, LDS-broadcast coefficient reads.
// ---------------------------------------------------------------------------
__global__ __launch_bounds__(PTS)
void gm_fused(const float* __restrict__ x,
              const float* __restrict__ centers,
              const float* __restrict__ cov,
              float* __restrict__ out)
{
    __shared__ float a[F_DIM][F_DIM + 1];   // fallback: Cholesky workspace
    __shared__ float yv[F_DIM][68];         // fallback: Linv rows (16B-aligned)
    __shared__ float Ds[GPB * F_DIM];       // raw diag -> rs (diag gaussians)
    __shared__ float Ms[GPB * F_DIM];       // whitened means
    __shared__ float Kc[GPB];               // logdet + F*log2pi
    __shared__ int   flags[GPB];            // 0 = diagonal, 1 = general

    const int t = threadIdx.x;
    const int pb = blockIdx.x >> 3;
    const int g0 = (blockIdx.x & 7) * GPB;
    const size_t p = (size_t)pb * PTS + t;

    if (t < GPB) flags[t] = 0;

    // This thread's x row -> registers (issued early; overlaps the cov scan)
    float xr[F_DIM];
    const float4* xp = (const float4*)(x + p * F_DIM);
#pragma unroll
    for (int j = 0; j < F_DIM / 4; ++j) {
        const float4 v = xp[j];
        xr[4 * j + 0] = v.x; xr[4 * j + 1] = v.y;
        xr[4 * j + 2] = v.z; xr[4 * j + 3] = v.w;
    }
    __syncthreads();   // flags init visible

    // ---- 1. scan 8 covariances: diag capture + off-diag check ----
    for (int gi = 0; gi < GPB; ++gi) {
        const float4* cov4 =
            (const float4*)(cov + (size_t)(g0 + gi) * F_DIM * F_DIM);
        int bad = 0;
#pragma unroll
        for (int i = 0; i < 4; ++i) {
            const float4 v = cov4[i * PTS + t];
            const int base = (i * PTS + t) * 4;
            const float vv[4] = {v.x, v.y, v.z, v.w};
#pragma unroll
            for (int c = 0; c < 4; ++c) {
                const int flat = base + c;
                const int r = flat >> 6, col = flat & 63;
                if (r == col) Ds[gi * F_DIM + r] = vv[c];
                else if (vv[c] != 0.0f) bad = 1;
            }
        }
        if (bad) flags[gi] = 1;   // benign same-value race
    }
    __syncthreads();

    // ---- 2. closed-form coefficients for diagonal gaussians (wave 0) ----
    if (t < F_DIM) {
        for (int gi = 0; gi < GPB; ++gi) {
            if (flags[gi] == 0) {   // uniform across wave 0
                const int g = g0 + gi;
                const float d  = Ds[gi * F_DIM + t];
                const float rs = 1.0f / sqrtf(d);
                Ds[gi * F_DIM + t] = rs;
                Ms[gi * F_DIM + t] = centers[g * F_DIM + t] * rs;
                float lg = logf(d);
#pragma unroll
                for (int off = 1; off < 64; off <<= 1) lg += __shfl_xor(lg, off);
                if (t == 0) Kc[gi] = lg + (float)F_DIM * LOG2PI;
            }
        }
    }
    __syncthreads();

    // ---- 3+4. per-gaussian maha + exp ----
    float o[GPB];
    for (int gi = 0; gi < GPB; ++gi) {
        const int g = g0 + gi;
        float maha = 0.0f;

        if (flags[gi] == 0) {
            // ---- diagonal: z_j = x_j*rs_j - m_j ----
            const float4* dv = (const float4*)(Ds + gi * F_DIM);
            const float4* mv = (const float4*)(Ms + gi * F_DIM);
            float m0 = 0.0f, m1 = 0.0f, m2 = 0.0f, m3 = 0.0f;
#pragma unroll
            for (int j = 0; j < F_DIM / 4; ++j) {
                const float4 d = dv[j];   // wave-uniform -> LDS broadcast
                const float4 m = mv[j];
                const float z0 = fmaf(xr[4 * j + 0], d.x, -m.x);
                const float z1 = fmaf(xr[4 * j + 1], d.y, -m.y);
                const float z2 = fmaf(xr[4 * j + 2], d.z, -m.z);
                const float z3 = fmaf(xr[4 * j + 3], d.w, -m.w);
                m0 = fmaf(z0, z0, m0);
                m1 = fmaf(z1, z1, m1);
                m2 = fmaf(z2, z2, m2);
                m3 = fmaf(z3, z3, m3);
            }
            maha = (m0 + m1) + (m2 + m3);
        } else {
            // ---- general fallback: block-local Cholesky + inverse ----
            __syncthreads();   // yv/a reuse across general gi's
            if (t < F_DIM)
                for (int j = 0; j < F_DIM; ++j)
                    a[t][j] = cov[(size_t)g * F_DIM * F_DIM + t * F_DIM + j];
            __syncthreads();

            for (int j = 0; j < F_DIM; ++j) {
                if (t == j) a[j][j] = sqrtf(a[j][j]);
                __syncthreads();
                if (t < F_DIM && t > j) a[t][j] /= a[j][j];
                __syncthreads();
                if (t < F_DIM && t > j) {
                    const float ltj = a[t][j];
                    for (int k = j + 1; k <= t; ++k) a[t][k] -= ltj * a[k][j];
                }
                __syncthreads();
            }

            if (t < F_DIM) {   // thread t owns column t of Linv
                const int c = t;
                for (int i = 0; i < c; ++i) yv[i][c] = 0.0f;
                yv[c][c] = 1.0f / a[c][c];
                for (int i = c + 1; i < F_DIM; ++i) {
                    float s = 0.0f;
                    for (int k = c; k < i; ++k) s += a[i][k] * yv[k][c];
                    yv[i][c] = -s / a[i][i];
                }
            }
            __syncthreads();

            if (t < F_DIM) {
                const float* cg = centers + g * F_DIM;
                float s = 0.0f;
                for (int j = 0; j <= t; ++j) s += yv[t][j] * cg[j];
                Ms[gi * F_DIM + t] = s;
                float lg = logf(a[t][t]);
#pragma unroll
                for (int off = 1; off < 64; off <<= 1) lg += __shfl_xor(lg, off);
                if (t == 0) Kc[gi] = 2.0f * lg + (float)F_DIM * LOG2PI;
            }
            __syncthreads();

#pragma unroll 8
            for (int i = 0; i < F_DIM; ++i) {
                const float4* row = (const float4*)(&yv[i][0]);
                float a0 = 0.0f, a1 = 0.0f, a2 = 0.0f, a3 = 0.0f;
#pragma unroll
                for (int j = 0; j < F_DIM / 4; ++j) {
                    const float4 v = row[j];
                    a0 = fmaf(v.x, xr[4 * j + 0], a0);
                    a1 = fmaf(v.y, xr[4 * j + 1], a1);
                    a2 = fmaf(v.z, xr[4 * j + 2], a2);
                    a3 = fmaf(v.w, xr[4 * j + 3], a3);
                }
                const float z = ((a0 + a2) + (a1 + a3)) - Ms[gi * F_DIM + i];
                maha = fmaf(z, z, maha);
            }
        }
        o[gi] = __expf(-0.5f * (maha + Kc[gi]));
    }

    // ---- store: 2 x float4 per thread (32 B contiguous) ----
    float4 r0, r1;
    r0.x = o[0]; r0.y = o[1]; r0.z = o[2]; r0.w = o[3];
    r1.x = o[4]; r1.y = o[5]; r1.z = o[6]; r1.w = o[7];
    float4* op = (float4*)(out + p * G_DIM + g0);
    op[0] = r0;
    op[1] = r1;
}

// ---------------------------------------------------------------------------
extern "C" void kernel_launch(void* const* d_in, const int* in_sizes, int n_in,
                              void* d_out, int out_size, void* d_ws, size_t ws_size,
                              hipStream_t stream) {
    const float* x       = (const float*)d_in[0];
    const float* centers = (const float*)d_in[1];
    const float* cov     = (const float*)d_in[2];
    float* out = (float*)d_out;

    const int npts = in_sizes[0] / F_DIM;        // 16384
    const int nblk = (npts / PTS) * (G_DIM / GPB);  // 64 * 8 = 512

    gm_fused<<<nblk, PTS, 0, stream>>>(x, centers, cov, out);
}

// Round 8
// 20.392 us; speedup vs baseline: 1.6777x; 1.6777x over previous
//
#include <hip/hip_runtime.h>
#include <math.h>

#define F_DIM 64
#define G_DIM 64
#define PTS 256   // threads per block
#define GPB 8     // gaussians per block (general/mixed path)
#define PPW 8     // points per wave (diag path); block = 4 waves = 32 points
#define LOG2PI 1.8378770664093453f

// ---------------------------------------------------------------------------
// Setup: one block (64 threads = 1 wave) per gaussian.
// Diag fast path: closed-form coefficients; writes BOTH row-major (diagv/mvec,
// for the mixed fallback) and transposed-interleaved cmT[j][g]={d,m} (for the
// register-resident transposed main path). No Ainv fill, no Cholesky.
// Fallback: Cholesky + triangular inverse, writes Ainv.
// gflag[g] written unconditionally (0=diag, 1=general) -> no memset needed.
// ---------------------------------------------------------------------------
__global__ __launch_bounds__(64)
void gm_setup(const float* __restrict__ centers,
              const float* __restrict__ cov,
              float* __restrict__ Ainv,    // G*F*F  (general path only)
              float* __restrict__ diagv,   // G*F    row-major diag of Linv
              float* __restrict__ mvec,    // G*F    row-major m
              float* __restrict__ cmT,     // F*G*2  transposed {d,m} pairs
              float* __restrict__ kconst,  // G
              int*   __restrict__ gflag)   // G
{
    __shared__ float a[F_DIM][F_DIM + 1];
    __shared__ float y[F_DIM][F_DIM + 1];
    __shared__ float ld[F_DIM];
    __shared__ float dsh[F_DIM];
    const int g = blockIdx.x;
    const int t = threadIdx.x;   // 0..63
    const float* covg = cov + (size_t)g * F_DIM * F_DIM;

    // Coalesced sweep: check off-diagonals, capture diagonal values.
    int bad = 0;
    const float4* cov4 = (const float4*)covg;
#pragma unroll
    for (int i = 0; i < 16; ++i) {
        const float4 v = cov4[i * 64 + t];
        const int base = (i * 64 + t) * 4;
        const float vv[4] = {v.x, v.y, v.z, v.w};
#pragma unroll
        for (int c = 0; c < 4; ++c) {
            const int flat = base + c;
            const int r = flat >> 6, col = flat & 63;
            if (r == col) dsh[r] = vv[c];
            else if (vv[c] != 0.0f) bad = 1;
        }
    }
    const unsigned long long anybad = __ballot(bad);
    __syncthreads();

    if (t == 0) gflag[g] = (anybad != 0ull) ? 1 : 0;

    if (anybad == 0ull) {
        // -------- diagonal fast path: coefficients only --------
        const float d  = dsh[t];
        const float rs = 1.0f / sqrtf(d);
        const float m  = centers[g * F_DIM + t] * rs;
        diagv[g * F_DIM + t] = rs;
        mvec[g * F_DIM + t]  = m;
        float2 dm; dm.x = rs; dm.y = m;
        *(float2*)(cmT + (size_t)(t * G_DIM + g) * 2) = dm;  // [dim][g]

        float lg = logf(d);
#pragma unroll
        for (int off = 1; off < 64; off <<= 1) lg += __shfl_xor(lg, off);
        if (t == 0) kconst[g] = lg + (float)F_DIM * LOG2PI;
        return;
    }

    // -------- general fallback: Cholesky + inverse --------
    for (int j = 0; j < F_DIM; ++j) a[t][j] = covg[t * F_DIM + j];
    __syncthreads();

    for (int j = 0; j < F_DIM; ++j) {
        if (t == j) a[j][j] = sqrtf(a[j][j]);
        __syncthreads();
        if (t > j) a[t][j] /= a[j][j];
        __syncthreads();
        if (t > j) {
            const float ltj = a[t][j];
            for (int k = j + 1; k <= t; ++k) a[t][k] -= ltj * a[k][j];
        }
        __syncthreads();
    }

    ld[t] = logf(a[t][t]);

    {   // thread t owns column t of Linv
        const int c = t;
        for (int i = 0; i < c; ++i) y[i][c] = 0.0f;
        y[c][c] = 1.0f / a[c][c];
        for (int i = c + 1; i < F_DIM; ++i) {
            float s = 0.0f;
            for (int k = c; k < i; ++k) s += a[i][k] * y[k][c];
            y[i][c] = -s / a[i][i];
        }
    }
    __syncthreads();

    for (int j = 0; j < F_DIM; ++j)
        Ainv[(size_t)g * F_DIM * F_DIM + t * F_DIM + j] = y[t][j];
    diagv[g * F_DIM + t] = y[t][t];

    const float* cg = centers + g * F_DIM;
    float s = 0.0f;
    for (int j = 0; j <= t; ++j) s += y[t][j] * cg[j];
    mvec[g * F_DIM + t] = s;

    if (t == 0) {
        float sum = 0.0f;
        for (int j = 0; j < F_DIM; ++j) sum += ld[j];
        kconst[g] = 2.0f * sum + (float)F_DIM * LOG2PI;
    }
}

// ---------------------------------------------------------------------------
// Main, 1D grid of npts/32 blocks x 256 threads.
// All-diag fast path (transposed): lane = gaussian, coefficients in VGPRs,
//   x rows read wave-uniformly (broadcast), TWO points in flight per
//   iteration (paired loads + independent accumulator chains -> 2x MLP/ILP).
// Mixed/general fallback: decode pblk = bid>>3, g0 = (bid&7)*GPB -> identical
//   work split to the old (npts/256, 8) 2D grid.
// ---------------------------------------------------------------------------
__global__ __launch_bounds__(PTS)
void gm_main(const float* __restrict__ x,
             const float* __restrict__ Ainv,
             const float* __restrict__ diagv,
             const float* __restrict__ mvec,
             const float* __restrict__ cmT,
             const float* __restrict__ kconst,
             const int* __restrict__ gflag,
             float* __restrict__ out)
{
    __shared__ float As[F_DIM * F_DIM];   // general path only
    __shared__ float Ds[GPB * F_DIM];
    __shared__ float Ms[GPB * F_DIM];
    __shared__ float Kc[GPB];
    const int t = threadIdx.x;
    const int lane = t & 63;

    // Block-uniform: every wave's lanes 0..63 read gflag[0..63].
    const int anyoff = __any(gflag[lane] != 0);

    if (!anyoff) {
        // ---------------- transposed all-diag fast path ----------------
        // Coefficients for gaussian `lane` -> registers (loaded coalesced).
        float2 dm[F_DIM];
        const float2* cm = (const float2*)cmT + lane;   // stride G_DIM float2s
#pragma unroll
        for (int j = 0; j < F_DIM; ++j) dm[j] = cm[(size_t)j * G_DIM];
        const float kg = kconst[lane];

        const int w = __builtin_amdgcn_readfirstlane(t >> 6);
        const int pbase = blockIdx.x * (4 * PPW) + w * PPW;

        for (int i = 0; i < PPW; i += 2) {
            const int pa = pbase + i, pb = pbase + i + 1;
            const float4* xa = (const float4*)(x + (size_t)pa * F_DIM);
            const float4* xb = (const float4*)(x + (size_t)pb * F_DIM);
            float a0 = 0.0f, a1 = 0.0f, a2 = 0.0f, a3 = 0.0f;
            float b0 = 0.0f, b1 = 0.0f, b2 = 0.0f, b3 = 0.0f;
#pragma unroll
            for (int j4 = 0; j4 < F_DIM / 4; ++j4) {
                const float4 va = xa[j4];   // wave-uniform -> broadcast
                const float4 vb = xb[j4];
                const float2 c0 = dm[4 * j4 + 0];
                const float2 c1 = dm[4 * j4 + 1];
                const float2 c2 = dm[4 * j4 + 2];
                const float2 c3 = dm[4 * j4 + 3];
                float z;
                z = fmaf(va.x, c0.x, -c0.y); a0 = fmaf(z, z, a0);
                z = fmaf(va.y, c1.x, -c1.y); a1 = fmaf(z, z, a1);
                z = fmaf(va.z, c2.x, -c2.y); a2 = fmaf(z, z, a2);
                z = fmaf(va.w, c3.x, -c3.y); a3 = fmaf(z, z, a3);
                z = fmaf(vb.x, c0.x, -c0.y); b0 = fmaf(z, z, b0);
                z = fmaf(vb.y, c1.x, -c1.y); b1 = fmaf(z, z, b1);
                z = fmaf(vb.z, c2.x, -c2.y); b2 = fmaf(z, z, b2);
                z = fmaf(vb.w, c3.x, -c3.y); b3 = fmaf(z, z, b3);
            }
            out[(size_t)pa * G_DIM + lane] =
                __expf(-0.5f * (((a0 + a1) + (a2 + a3)) + kg));
            out[(size_t)pb * G_DIM + lane] =
                __expf(-0.5f * (((b0 + b1) + (b2 + b3)) + kg));
        }
        return;
    }

    // ---------------- mixed / general path ----------------
    const int pblk = blockIdx.x >> 3;
    const int g0   = (blockIdx.x & 7) * GPB;
    const size_t p = (size_t)pblk * PTS + t;

    float xr[F_DIM];
    const float4* xp = (const float4*)(x + p * F_DIM);
#pragma unroll
    for (int j = 0; j < F_DIM / 4; ++j) {
        const float4 v = xp[j];
        xr[4 * j + 0] = v.x; xr[4 * j + 1] = v.y;
        xr[4 * j + 2] = v.z; xr[4 * j + 3] = v.w;
    }

    ((float2*)Ds)[t] = ((const float2*)(diagv + g0 * F_DIM))[t];
    ((float2*)Ms)[t] = ((const float2*)(mvec  + g0 * F_DIM))[t];
    if (t < GPB) Kc[t] = kconst[g0 + t];
    __syncthreads();

    float o[GPB];
    for (int gi = 0; gi < GPB; ++gi) {
        const int g = g0 + gi;
        float maha = 0.0f;
        if (gflag[g] == 0) {           // block-uniform branch
            const float4* dv = (const float4*)(Ds + gi * F_DIM);
            const float4* mv = (const float4*)(Ms + gi * F_DIM);
            float m0 = 0.0f, m1 = 0.0f, m2 = 0.0f, m3 = 0.0f;
#pragma unroll
            for (int j = 0; j < F_DIM / 4; ++j) {
                const float4 d = dv[j];
                const float4 m = mv[j];
                const float z0 = fmaf(xr[4 * j + 0], d.x, -m.x);
                const float z1 = fmaf(xr[4 * j + 1], d.y, -m.y);
                const float z2 = fmaf(xr[4 * j + 2], d.z, -m.z);
                const float z3 = fmaf(xr[4 * j + 3], d.w, -m.w);
                m0 = fmaf(z0, z0, m0);
                m1 = fmaf(z1, z1, m1);
                m2 = fmaf(z2, z2, m2);
                m3 = fmaf(z3, z3, m3);
            }
            maha = (m0 + m1) + (m2 + m3);
        } else {
            __syncthreads();   // As reuse (uniform: gflag same blockwide)
            const float4* Ag = (const float4*)(Ainv + (size_t)g * F_DIM * F_DIM);
            float4* As4 = (float4*)As;
#pragma unroll
            for (int r = 0; r < 4; ++r) As4[r * PTS + t] = Ag[r * PTS + t];
            __syncthreads();
#pragma unroll 8
            for (int i = 0; i < F_DIM; ++i) {
                const float4* row = (const float4*)(As + i * F_DIM);
                float a0 = 0.0f, a1 = 0.0f, a2 = 0.0f, a3 = 0.0f;
#pragma unroll
                for (int j = 0; j < F_DIM / 4; ++j) {
                    const float4 v = row[j];
                    a0 = fmaf(v.x, xr[4 * j + 0], a0);
                    a1 = fmaf(v.y, xr[4 * j + 1], a1);
                    a2 = fmaf(v.z, xr[4 * j + 2], a2);
                    a3 = fmaf(v.w, xr[4 * j + 3], a3);
                }
                const float z = ((a0 + a2) + (a1 + a3)) - Ms[gi * F_DIM + i];
                maha = fmaf(z, z, maha);
            }
        }
        o[gi] = __expf(-0.5f * (maha + Kc[gi]));
    }
#pragma unroll
    for (int gi = 0; gi < GPB; ++gi) out[p * G_DIM + g0 + gi] = o[gi];
}

// ---------------------------------------------------------------------------
extern "C" void kernel_launch(void* const* d_in, const int* in_sizes, int n_in,
                              void* d_out, int out_size, void* d_ws, size_t ws_size,
                              hipStream_t stream) {
    const float* x       = (const float*)d_in[0];
    const float* centers = (const float*)d_in[1];
    const float* cov     = (const float*)d_in[2];
    float* out = (float*)d_out;

    char* ws = (char*)d_ws;
    const size_t ainv_bytes = (size_t)G_DIM * F_DIM * F_DIM * sizeof(float); // 1 MiB
    const size_t gf_bytes   = (size_t)G_DIM * F_DIM * sizeof(float);         // 16 KiB
    float* Ainv   = (float*)(ws);
    float* mvec   = (float*)(ws + ainv_bytes);
    float* kconst = (float*)(ws + ainv_bytes + gf_bytes);
    float* diagv  = (float*)(ws + ainv_bytes + gf_bytes + 1024);
    int*   gflag  = (int*)  (ws + ainv_bytes + gf_bytes + 1024 + gf_bytes);
    float* cmT    = (float*)(ws + ainv_bytes + gf_bytes + 1024 + gf_bytes + 1024);

    const int npts = in_sizes[0] / F_DIM;   // 16384

    gm_setup<<<G_DIM, F_DIM, 0, stream>>>(centers, cov, Ainv, diagv, mvec,
                                          cmT, kconst, gflag);

    gm_main<<<npts / (4 * PPW), PTS, 0, stream>>>(x, Ainv, diagv, mvec, cmT,
                                                  kconst, gflag, out);
}

// Round 9
// 19.180 us; speedup vs baseline: 1.7838x; 1.0632x over previous
//
#include <hip/hip_runtime.h>
#include <math.h>

#define F_DIM 64
#define G_DIM 64
#define PTS 256   // threads per block
#define GPB 8     // gaussians per block (general/mixed path)
#define PPW 8     // points per wave (diag path); block = 4 waves = 32 points
#define LOG2PI 1.8378770664093453f

// ---------------------------------------------------------------------------
// Setup: one block (64 threads = 1 wave) per gaussian.
// Diag fast path: closed-form coefficients; writes row-major (diagv/mvec, for
// the mixed fallback) and transposed-interleaved cmT[j][g]={d,m} (for the
// register-resident transposed main path). No Ainv fill, no Cholesky.
// Fallback: Cholesky + triangular inverse, writes Ainv.
// gflag[g] written unconditionally (0=diag, 1=general) -> no memset needed.
// ---------------------------------------------------------------------------
__global__ __launch_bounds__(64)
void gm_setup(const float* __restrict__ centers,
              const float* __restrict__ cov,
              float* __restrict__ Ainv,    // G*F*F  (general path only)
              float* __restrict__ diagv,   // G*F    row-major diag of Linv
              float* __restrict__ mvec,    // G*F    row-major m
              float* __restrict__ cmT,     // F*G*2  transposed {d,m} pairs
              float* __restrict__ kconst,  // G
              int*   __restrict__ gflag)   // G
{
    __shared__ float a[F_DIM][F_DIM + 1];
    __shared__ float y[F_DIM][F_DIM + 1];
    __shared__ float ld[F_DIM];
    __shared__ float dsh[F_DIM];
    const int g = blockIdx.x;
    const int t = threadIdx.x;   // 0..63
    const float* covg = cov + (size_t)g * F_DIM * F_DIM;

    // Coalesced sweep: check off-diagonals, capture diagonal values.
    int bad = 0;
    const float4* cov4 = (const float4*)covg;
#pragma unroll
    for (int i = 0; i < 16; ++i) {
        const float4 v = cov4[i * 64 + t];
        const int base = (i * 64 + t) * 4;
        const float vv[4] = {v.x, v.y, v.z, v.w};
#pragma unroll
        for (int c = 0; c < 4; ++c) {
            const int flat = base + c;
            const int r = flat >> 6, col = flat & 63;
            if (r == col) dsh[r] = vv[c];
            else if (vv[c] != 0.0f) bad = 1;
        }
    }
    const unsigned long long anybad = __ballot(bad);
    __syncthreads();

    if (t == 0) gflag[g] = (anybad != 0ull) ? 1 : 0;

    if (anybad == 0ull) {
        // -------- diagonal fast path: coefficients only --------
        const float d  = dsh[t];
        const float rs = 1.0f / sqrtf(d);
        const float m  = centers[g * F_DIM + t] * rs;
        diagv[g * F_DIM + t] = rs;
        mvec[g * F_DIM + t]  = m;
        float2 dm; dm.x = rs; dm.y = m;
        *(float2*)(cmT + (size_t)(t * G_DIM + g) * 2) = dm;  // [dim][g]

        float lg = logf(d);
#pragma unroll
        for (int off = 1; off < 64; off <<= 1) lg += __shfl_xor(lg, off);
        if (t == 0) kconst[g] = lg + (float)F_DIM * LOG2PI;
        return;
    }

    // -------- general fallback: Cholesky + inverse --------
    for (int j = 0; j < F_DIM; ++j) a[t][j] = covg[t * F_DIM + j];
    __syncthreads();

    for (int j = 0; j < F_DIM; ++j) {
        if (t == j) a[j][j] = sqrtf(a[j][j]);
        __syncthreads();
        if (t > j) a[t][j] /= a[j][j];
        __syncthreads();
        if (t > j) {
            const float ltj = a[t][j];
            for (int k = j + 1; k <= t; ++k) a[t][k] -= ltj * a[k][j];
        }
        __syncthreads();
    }

    ld[t] = logf(a[t][t]);

    {   // thread t owns column t of Linv
        const int c = t;
        for (int i = 0; i < c; ++i) y[i][c] = 0.0f;
        y[c][c] = 1.0f / a[c][c];
        for (int i = c + 1; i < F_DIM; ++i) {
            float s = 0.0f;
            for (int k = c; k < i; ++k) s += a[i][k] * y[k][c];
            y[i][c] = -s / a[i][i];
        }
    }
    __syncthreads();

    for (int j = 0; j < F_DIM; ++j)
        Ainv[(size_t)g * F_DIM * F_DIM + t * F_DIM + j] = y[t][j];
    diagv[g * F_DIM + t] = y[t][t];

    const float* cg = centers + g * F_DIM;
    float s = 0.0f;
    for (int j = 0; j <= t; ++j) s += y[t][j] * cg[j];
    mvec[g * F_DIM + t] = s;

    if (t == 0) {
        float sum = 0.0f;
        for (int j = 0; j < F_DIM; ++j) sum += ld[j];
        kconst[g] = 2.0f * sum + (float)F_DIM * LOG2PI;
    }
}

// ---------------------------------------------------------------------------
// Main, 1D grid of npts/32 blocks x 256 threads.
// All-diag fast path (transposed): cmT (32 KB, the WHOLE coefficient table)
//   is staged into LDS once per block (coalesced); each lane then fills its
//   64 float2 registers via ds_read_b64 (2-way bank alias = free). Lane =
//   gaussian, x rows read wave-uniformly, two points in flight per iteration.
// Mixed/general fallback: decode pblk = bid>>3, g0 = (bid&7)*GPB -> identical
//   work split to the old (npts/256, 8) 2D grid.
// ---------------------------------------------------------------------------
__global__ __launch_bounds__(PTS)
void gm_main(const float* __restrict__ x,
             const float* __restrict__ Ainv,
             const float* __restrict__ diagv,
             const float* __restrict__ mvec,
             const float* __restrict__ cmT,
             const float* __restrict__ kconst,
             const int* __restrict__ gflag,
             float* __restrict__ out)
{
    __shared__ union {
        float2 cmS[G_DIM * F_DIM];           // diag path: [j][g] {rs, m} 32 KB
        struct {                             // general/mixed path
            float As[F_DIM * F_DIM];
            float Ds[GPB * F_DIM];
            float Ms[GPB * F_DIM];
            float Kc[GPB];
        } gen;
    } sh;
    const int t = threadIdx.x;
    const int lane = t & 63;

    // Block-uniform: every wave's lanes 0..63 read gflag[0..63].
    const int anyoff = __any(gflag[lane] != 0);

    if (!anyoff) {
        // ---------------- transposed all-diag fast path ----------------
        // Stage the full coefficient table once per block (coalesced float4).
        {
            const float4* src = (const float4*)cmT;   // 2048 float4
            float4* dst = (float4*)sh.cmS;
#pragma unroll
            for (int r = 0; r < 8; ++r) dst[r * PTS + t] = src[r * PTS + t];
        }
        const float kg = kconst[lane];
        __syncthreads();

        // Per-lane register fill from LDS (ds_read_b64, 2-way alias -> free).
        float2 dm[F_DIM];
#pragma unroll
        for (int j = 0; j < F_DIM; ++j) dm[j] = sh.cmS[j * G_DIM + lane];

        const int w = __builtin_amdgcn_readfirstlane(t >> 6);
        const int pbase = blockIdx.x * (4 * PPW) + w * PPW;

        for (int i = 0; i < PPW; i += 2) {
            const int pa = pbase + i, pb = pbase + i + 1;
            const float4* xa = (const float4*)(x + (size_t)pa * F_DIM);
            const float4* xb = (const float4*)(x + (size_t)pb * F_DIM);
            float a0 = 0.0f, a1 = 0.0f, a2 = 0.0f, a3 = 0.0f;
            float b0 = 0.0f, b1 = 0.0f, b2 = 0.0f, b3 = 0.0f;
#pragma unroll
            for (int j4 = 0; j4 < F_DIM / 4; ++j4) {
                const float4 va = xa[j4];   // wave-uniform -> broadcast
                const float4 vb = xb[j4];
                const float2 c0 = dm[4 * j4 + 0];
                const float2 c1 = dm[4 * j4 + 1];
                const float2 c2 = dm[4 * j4 + 2];
                const float2 c3 = dm[4 * j4 + 3];
                float z;
                z = fmaf(va.x, c0.x, -c0.y); a0 = fmaf(z, z, a0);
                z = fmaf(va.y, c1.x, -c1.y); a1 = fmaf(z, z, a1);
                z = fmaf(va.z, c2.x, -c2.y); a2 = fmaf(z, z, a2);
                z = fmaf(va.w, c3.x, -c3.y); a3 = fmaf(z, z, a3);
                z = fmaf(vb.x, c0.x, -c0.y); b0 = fmaf(z, z, b0);
                z = fmaf(vb.y, c1.x, -c1.y); b1 = fmaf(z, z, b1);
                z = fmaf(vb.z, c2.x, -c2.y); b2 = fmaf(z, z, b2);
                z = fmaf(vb.w, c3.x, -c3.y); b3 = fmaf(z, z, b3);
            }
            out[(size_t)pa * G_DIM + lane] =
                __expf(-0.5f * (((a0 + a1) + (a2 + a3)) + kg));
            out[(size_t)pb * G_DIM + lane] =
                __expf(-0.5f * (((b0 + b1) + (b2 + b3)) + kg));
        }
        return;
    }

    // ---------------- mixed / general path ----------------
    const int pblk = blockIdx.x >> 3;
    const int g0   = (blockIdx.x & 7) * GPB;
    const size_t p = (size_t)pblk * PTS + t;

    float xr[F_DIM];
    const float4* xp = (const float4*)(x + p * F_DIM);
#pragma unroll
    for (int j = 0; j < F_DIM / 4; ++j) {
        const float4 v = xp[j];
        xr[4 * j + 0] = v.x; xr[4 * j + 1] = v.y;
        xr[4 * j + 2] = v.z; xr[4 * j + 3] = v.w;
    }

    ((float2*)sh.gen.Ds)[t] = ((const float2*)(diagv + g0 * F_DIM))[t];
    ((float2*)sh.gen.Ms)[t] = ((const float2*)(mvec  + g0 * F_DIM))[t];
    if (t < GPB) sh.gen.Kc[t] = kconst[g0 + t];
    __syncthreads();

    float o[GPB];
    for (int gi = 0; gi < GPB; ++gi) {
        const int g = g0 + gi;
        float maha = 0.0f;
        if (gflag[g] == 0) {           // block-uniform branch
            const float4* dv = (const float4*)(sh.gen.Ds + gi * F_DIM);
            const float4* mv = (const float4*)(sh.gen.Ms + gi * F_DIM);
            float m0 = 0.0f, m1 = 0.0f, m2 = 0.0f, m3 = 0.0f;
#pragma unroll
            for (int j = 0; j < F_DIM / 4; ++j) {
                const float4 d = dv[j];
                const float4 m = mv[j];
                const float z0 = fmaf(xr[4 * j + 0], d.x, -m.x);
                const float z1 = fmaf(xr[4 * j + 1], d.y, -m.y);
                const float z2 = fmaf(xr[4 * j + 2], d.z, -m.z);
                const float z3 = fmaf(xr[4 * j + 3], d.w, -m.w);
                m0 = fmaf(z0, z0, m0);
                m1 = fmaf(z1, z1, m1);
                m2 = fmaf(z2, z2, m2);
                m3 = fmaf(z3, z3, m3);
            }
            maha = (m0 + m1) + (m2 + m3);
        } else {
            __syncthreads();   // As reuse (uniform: gflag same blockwide)
            const float4* Ag = (const float4*)(Ainv + (size_t)g * F_DIM * F_DIM);
            float4* As4 = (float4*)sh.gen.As;
#pragma unroll
            for (int r = 0; r < 4; ++r) As4[r * PTS + t] = Ag[r * PTS + t];
            __syncthreads();
#pragma unroll 8
            for (int i = 0; i < F_DIM; ++i) {
                const float4* row = (const float4*)(sh.gen.As + i * F_DIM);
                float a0 = 0.0f, a1 = 0.0f, a2 = 0.0f, a3 = 0.0f;
#pragma unroll
                for (int j = 0; j < F_DIM / 4; ++j) {
                    const float4 v = row[j];
                    a0 = fmaf(v.x, xr[4 * j + 0], a0);
                    a1 = fmaf(v.y, xr[4 * j + 1], a1);
                    a2 = fmaf(v.z, xr[4 * j + 2], a2);
                    a3 = fmaf(v.w, xr[4 * j + 3], a3);
                }
                const float z = ((a0 + a2) + (a1 + a3)) - sh.gen.Ms[gi * F_DIM + i];
                maha = fmaf(z, z, maha);
            }
        }
        o[gi] = __expf(-0.5f * (maha + sh.gen.Kc[gi]));
    }
#pragma unroll
    for (int gi = 0; gi < GPB; ++gi) out[p * G_DIM + g0 + gi] = o[gi];
}

// ---------------------------------------------------------------------------
extern "C" void kernel_launch(void* const* d_in, const int* in_sizes, int n_in,
                              void* d_out, int out_size, void* d_ws, size_t ws_size,
                              hipStream_t stream) {
    const float* x       = (const float*)d_in[0];
    const float* centers = (const float*)d_in[1];
    const float* cov     = (const float*)d_in[2];
    float* out = (float*)d_out;

    char* ws = (char*)d_ws;
    const size_t ainv_bytes = (size_t)G_DIM * F_DIM * F_DIM * sizeof(float); // 1 MiB
    const size_t gf_bytes   = (size_t)G_DIM * F_DIM * sizeof(float);         // 16 KiB
    float* Ainv   = (float*)(ws);
    float* mvec   = (float*)(ws + ainv_bytes);
    float* kconst = (float*)(ws + ainv_bytes + gf_bytes);
    float* diagv  = (float*)(ws + ainv_bytes + gf_bytes + 1024);
    int*   gflag  = (int*)  (ws + ainv_bytes + gf_bytes + 1024 + gf_bytes);
    float* cmT    = (float*)(ws + ainv_bytes + gf_bytes + 1024 + gf_bytes + 1024);

    const int npts = in_sizes[0] / F_DIM;   // 16384

    gm_setup<<<G_DIM, F_DIM, 0, stream>>>(centers, cov, Ainv, diagv, mvec,
                                          cmT, kconst, gflag);

    gm_main<<<npts / (4 * PPW), PTS, 0, stream>>>(x, Ainv, diagv, mvec, cmT,
                                                  kconst, gflag, out);
}

// Round 10
// 19.001 us; speedup vs baseline: 1.8005x; 1.0094x over previous
//
#include <hip/hip_runtime.h>
#include <math.h>

#define F_DIM 64
#define G_DIM 64
#define PTS 256   // threads per block
#define GPB 8     // gaussians per block (general/mixed path)
#define PPW 8     // points per wave (diag path); block = 4 waves = 32 points
#define LOG2PI 1.8378770664093453f

// ---------------------------------------------------------------------------
// Setup: one block (64 threads = 1 wave) per gaussian.
// Diag fast path: closed-form coefficients; writes row-major (diagv/mvec, for
// the mixed fallback) and transposed-interleaved cmT[j][g]={d,m} (for the
// register-resident transposed main path). No Ainv fill, no Cholesky.
// Fallback: Cholesky + triangular inverse, writes Ainv.
// gflag[g] written unconditionally (0=diag, 1=general) -> no memset needed.
// ---------------------------------------------------------------------------
__global__ __launch_bounds__(64)
void gm_setup(const float* __restrict__ centers,
              const float* __restrict__ cov,
              float* __restrict__ Ainv,    // G*F*F  (general path only)
              float* __restrict__ diagv,   // G*F    row-major diag of Linv
              float* __restrict__ mvec,    // G*F    row-major m
              float* __restrict__ cmT,     // F*G*2  transposed {d,m} pairs
              float* __restrict__ kconst,  // G
              int*   __restrict__ gflag)   // G
{
    __shared__ float a[F_DIM][F_DIM + 1];
    __shared__ float y[F_DIM][F_DIM + 1];
    __shared__ float ld[F_DIM];
    __shared__ float dsh[F_DIM];
    const int g = blockIdx.x;
    const int t = threadIdx.x;   // 0..63
    const float* covg = cov + (size_t)g * F_DIM * F_DIM;

    // Coalesced sweep: check off-diagonals, capture diagonal values.
    int bad = 0;
    const float4* cov4 = (const float4*)covg;
#pragma unroll
    for (int i = 0; i < 16; ++i) {
        const float4 v = cov4[i * 64 + t];
        const int base = (i * 64 + t) * 4;
        const float vv[4] = {v.x, v.y, v.z, v.w};
#pragma unroll
        for (int c = 0; c < 4; ++c) {
            const int flat = base + c;
            const int r = flat >> 6, col = flat & 63;
            if (r == col) dsh[r] = vv[c];
            else if (vv[c] != 0.0f) bad = 1;
        }
    }
    const unsigned long long anybad = __ballot(bad);
    __syncthreads();

    if (t == 0) gflag[g] = (anybad != 0ull) ? 1 : 0;

    if (anybad == 0ull) {
        // -------- diagonal fast path: coefficients only --------
        const float d  = dsh[t];
        const float rs = 1.0f / sqrtf(d);
        const float m  = centers[g * F_DIM + t] * rs;
        diagv[g * F_DIM + t] = rs;
        mvec[g * F_DIM + t]  = m;
        float2 dm; dm.x = rs; dm.y = m;
        *(float2*)(cmT + (size_t)(t * G_DIM + g) * 2) = dm;  // [dim][g]

        float lg = logf(d);
#pragma unroll
        for (int off = 1; off < 64; off <<= 1) lg += __shfl_xor(lg, off);
        if (t == 0) kconst[g] = lg + (float)F_DIM * LOG2PI;
        return;
    }

    // -------- general fallback: Cholesky + inverse --------
    for (int j = 0; j < F_DIM; ++j) a[t][j] = covg[t * F_DIM + j];
    __syncthreads();

    for (int j = 0; j < F_DIM; ++j) {
        if (t == j) a[j][j] = sqrtf(a[j][j]);
        __syncthreads();
        if (t > j) a[t][j] /= a[j][j];
        __syncthreads();
        if (t > j) {
            const float ltj = a[t][j];
            for (int k = j + 1; k <= t; ++k) a[t][k] -= ltj * a[k][j];
        }
        __syncthreads();
    }

    ld[t] = logf(a[t][t]);

    {   // thread t owns column t of Linv
        const int c = t;
        for (int i = 0; i < c; ++i) y[i][c] = 0.0f;
        y[c][c] = 1.0f / a[c][c];
        for (int i = c + 1; i < F_DIM; ++i) {
            float s = 0.0f;
            for (int k = c; k < i; ++k) s += a[i][k] * y[k][c];
            y[i][c] = -s / a[i][i];
        }
    }
    __syncthreads();

    for (int j = 0; j < F_DIM; ++j)
        Ainv[(size_t)g * F_DIM * F_DIM + t * F_DIM + j] = y[t][j];
    diagv[g * F_DIM + t] = y[t][t];

    const float* cg = centers + g * F_DIM;
    float s = 0.0f;
    for (int j = 0; j <= t; ++j) s += y[t][j] * cg[j];
    mvec[g * F_DIM + t] = s;

    if (t == 0) {
        float sum = 0.0f;
        for (int j = 0; j < F_DIM; ++j) sum += ld[j];
        kconst[g] = 2.0f * sum + (float)F_DIM * LOG2PI;
    }
}

// ---------------------------------------------------------------------------
// Main, 1D grid of npts/32 blocks x 256 threads.
// All-diag fast path (transposed): cmT (32 KB, the WHOLE coefficient table)
//   is staged into LDS once per block (coalesced); each lane then fills its
//   64 float2 registers via ds_read_b64 (2-way bank alias = free). Lane =
//   gaussian, x rows read wave-uniformly, two points in flight per iteration.
// Mixed/general fallback: decode pblk = bid>>3, g0 = (bid&7)*GPB -> identical
//   work split to the old (npts/256, 8) 2D grid.
// ---------------------------------------------------------------------------
__global__ __launch_bounds__(PTS)
void gm_main(const float* __restrict__ x,
             const float* __restrict__ Ainv,
             const float* __restrict__ diagv,
             const float* __restrict__ mvec,
             const float* __restrict__ cmT,
             const float* __restrict__ kconst,
             const int* __restrict__ gflag,
             float* __restrict__ out)
{
    __shared__ union {
        float2 cmS[G_DIM * F_DIM];           // diag path: [j][g] {rs, m} 32 KB
        struct {                             // general/mixed path
            float As[F_DIM * F_DIM];
            float Ds[GPB * F_DIM];
            float Ms[GPB * F_DIM];
            float Kc[GPB];
        } gen;
    } sh;
    const int t = threadIdx.x;
    const int lane = t & 63;

    // Block-uniform: every wave's lanes 0..63 read gflag[0..63].
    const int anyoff = __any(gflag[lane] != 0);

    if (!anyoff) {
        // ---------------- transposed all-diag fast path ----------------
        // Stage the full coefficient table once per block (coalesced float4).
        {
            const float4* src = (const float4*)cmT;   // 2048 float4
            float4* dst = (float4*)sh.cmS;
#pragma unroll
            for (int r = 0; r < 8; ++r) dst[r * PTS + t] = src[r * PTS + t];
        }
        const float kg = kconst[lane];
        __syncthreads();

        // Per-lane register fill from LDS (ds_read_b64, 2-way alias -> free).
        float2 dm[F_DIM];
#pragma unroll
        for (int j = 0; j < F_DIM; ++j) dm[j] = sh.cmS[j * G_DIM + lane];

        const int w = __builtin_amdgcn_readfirstlane(t >> 6);
        const int pbase = blockIdx.x * (4 * PPW) + w * PPW;

        for (int i = 0; i < PPW; i += 2) {
            const int pa = pbase + i, pb = pbase + i + 1;
            const float4* xa = (const float4*)(x + (size_t)pa * F_DIM);
            const float4* xb = (const float4*)(x + (size_t)pb * F_DIM);
            float a0 = 0.0f, a1 = 0.0f, a2 = 0.0f, a3 = 0.0f;
            float b0 = 0.0f, b1 = 0.0f, b2 = 0.0f, b3 = 0.0f;
#pragma unroll
            for (int j4 = 0; j4 < F_DIM / 4; ++j4) {
                const float4 va = xa[j4];   // wave-uniform -> broadcast
                const float4 vb = xb[j4];
                const float2 c0 = dm[4 * j4 + 0];
                const float2 c1 = dm[4 * j4 + 1];
                const float2 c2 = dm[4 * j4 + 2];
                const float2 c3 = dm[4 * j4 + 3];
                float z;
                z = fmaf(va.x, c0.x, -c0.y); a0 = fmaf(z, z, a0);
                z = fmaf(va.y, c1.x, -c1.y); a1 = fmaf(z, z, a1);
                z = fmaf(va.z, c2.x, -c2.y); a2 = fmaf(z, z, a2);
                z = fmaf(va.w, c3.x, -c3.y); a3 = fmaf(z, z, a3);
                z = fmaf(vb.x, c0.x, -c0.y); b0 = fmaf(z, z, b0);
                z = fmaf(vb.y, c1.x, -c1.y); b1 = fmaf(z, z, b1);
                z = fmaf(vb.z, c2.x, -c2.y); b2 = fmaf(z, z, b2);
                z = fmaf(vb.w, c3.x, -c3.y); b3 = fmaf(z, z, b3);
            }
            out[(size_t)pa * G_DIM + lane] =
                __expf(-0.5f * (((a0 + a1) + (a2 + a3)) + kg));
            out[(size_t)pb * G_DIM + lane] =
                __expf(-0.5f * (((b0 + b1) + (b2 + b3)) + kg));
        }
        return;
    }

    // ---------------- mixed / general path ----------------
    const int pblk = blockIdx.x >> 3;
    const int g0   = (blockIdx.x & 7) * GPB;
    const size_t p = (size_t)pblk * PTS + t;

    float xr[F_DIM];
    const float4* xp = (const float4*)(x + p * F_DIM);
#pragma unroll
    for (int j = 0; j < F_DIM / 4; ++j) {
        const float4 v = xp[j];
        xr[4 * j + 0] = v.x; xr[4 * j + 1] = v.y;
        xr[4 * j + 2] = v.z; xr[4 * j + 3] = v.w;
    }

    ((float2*)sh.gen.Ds)[t] = ((const float2*)(diagv + g0 * F_DIM))[t];
    ((float2*)sh.gen.Ms)[t] = ((const float2*)(mvec  + g0 * F_DIM))[t];
    if (t < GPB) sh.gen.Kc[t] = kconst[g0 + t];
    __syncthreads();

    float o[GPB];
    for (int gi = 0; gi < GPB; ++gi) {
        const int g = g0 + gi;
        float maha = 0.0f;
        if (gflag[g] == 0) {           // block-uniform branch
            const float4* dv = (const float4*)(sh.gen.Ds + gi * F_DIM);
            const float4* mv = (const float4*)(sh.gen.Ms + gi * F_DIM);
            float m0 = 0.0f, m1 = 0.0f, m2 = 0.0f, m3 = 0.0f;
#pragma unroll
            for (int j = 0; j < F_DIM / 4; ++j) {
                const float4 d = dv[j];
                const float4 m = mv[j];
                const float z0 = fmaf(xr[4 * j + 0], d.x, -m.x);
                const float z1 = fmaf(xr[4 * j + 1], d.y, -m.y);
                const float z2 = fmaf(xr[4 * j + 2], d.z, -m.z);
                const float z3 = fmaf(xr[4 * j + 3], d.w, -m.w);
                m0 = fmaf(z0, z0, m0);
                m1 = fmaf(z1, z1, m1);
                m2 = fmaf(z2, z2, m2);
                m3 = fmaf(z3, z3, m3);
            }
            maha = (m0 + m1) + (m2 + m3);
        } else {
            __syncthreads();   // As reuse (uniform: gflag same blockwide)
            const float4* Ag = (const float4*)(Ainv + (size_t)g * F_DIM * F_DIM);
            float4* As4 = (float4*)sh.gen.As;
#pragma unroll
            for (int r = 0; r < 4; ++r) As4[r * PTS + t] = Ag[r * PTS + t];
            __syncthreads();
#pragma unroll 8
            for (int i = 0; i < F_DIM; ++i) {
                const float4* row = (const float4*)(sh.gen.As + i * F_DIM);
                float a0 = 0.0f, a1 = 0.0f, a2 = 0.0f, a3 = 0.0f;
#pragma unroll
                for (int j = 0; j < F_DIM / 4; ++j) {
                    const float4 v = row[j];
                    a0 = fmaf(v.x, xr[4 * j + 0], a0);
                    a1 = fmaf(v.y, xr[4 * j + 1], a1);
                    a2 = fmaf(v.z, xr[4 * j + 2], a2);
                    a3 = fmaf(v.w, xr[4 * j + 3], a3);
                }
                const float z = ((a0 + a2) + (a1 + a3)) - sh.gen.Ms[gi * F_DIM + i];
                maha = fmaf(z, z, maha);
            }
        }
        o[gi] = __expf(-0.5f * (maha + sh.gen.Kc[gi]));
    }
#pragma unroll
    for (int gi = 0; gi < GPB; ++gi) out[p * G_DIM + g0 + gi] = o[gi];
}

// ---------------------------------------------------------------------------
extern "C" void kernel_launch(void* const* d_in, const int* in_sizes, int n_in,
                              void* d_out, int out_size, void* d_ws, size_t ws_size,
                              hipStream_t stream) {
    const float* x       = (const float*)d_in[0];
    const float* centers = (const float*)d_in[1];
    const float* cov     = (const float*)d_in[2];
    float* out = (float*)d_out;

    char* ws = (char*)d_ws;
    const size_t ainv_bytes = (size_t)G_DIM * F_DIM * F_DIM * sizeof(float); // 1 MiB
    const size_t gf_bytes   = (size_t)G_DIM * F_DIM * sizeof(float);         // 16 KiB
    float* Ainv   = (float*)(ws);
    float* mvec   = (float*)(ws + ainv_bytes);
    float* kconst = (float*)(ws + ainv_bytes + gf_bytes);
    float* diagv  = (float*)(ws + ainv_bytes + gf_bytes + 1024);
    int*   gflag  = (int*)  (ws + ainv_bytes + gf_bytes + 1024 + gf_bytes);
    float* cmT    = (float*)(ws + ainv_bytes + gf_bytes + 1024 + gf_bytes + 1024);

    const int npts = in_sizes[0] / F_DIM;   // 16384

    gm_setup<<<G_DIM, F_DIM, 0, stream>>>(centers, cov, Ainv, diagv, mvec,
                                          cmT, kconst, gflag);

    gm_main<<<npts / (4 * PPW), PTS, 0, stream>>>(x, Ainv, diagv, mvec, cmT,
                                                  kconst, gflag, out);
}

// Round 11
// 17.788 us; speedup vs baseline: 1.9233x; 1.0682x over previous
//
#include <hip/hip_runtime.h>
#include <math.h>

#define F_DIM 64
#define G_DIM 64
#define PTS 256   // threads per block
#define GPB 8     // gaussians per block (general/mixed path)
#define PPW 4     // points per wave (diag path); block = 4 waves = 16 points
#define LOG2PI 1.8378770664093453f

// ---------------------------------------------------------------------------
// Setup: one block (256 threads = 4 waves) per gaussian.
// Scan phase uses all 4 waves (4 float4/thread) to cut exposed HBM latency.
// Diag fast path: closed-form coefficients on wave 0.
// Fallback: Cholesky + triangular inverse (t<64 work, block-wide barriers).
// gflag[g] written unconditionally (0=diag, 1=general) -> no memset needed.
// ---------------------------------------------------------------------------
__global__ __launch_bounds__(256)
void gm_setup(const float* __restrict__ centers,
              const float* __restrict__ cov,
              float* __restrict__ Ainv,    // G*F*F  (general path only)
              float* __restrict__ diagv,   // G*F    row-major diag of Linv
              float* __restrict__ mvec,    // G*F    row-major m
              float* __restrict__ cmT,     // F*G*2  transposed {d,m} pairs
              float* __restrict__ kconst,  // G
              int*   __restrict__ gflag)   // G
{
    __shared__ float a[F_DIM][F_DIM + 1];
    __shared__ float yv[F_DIM][F_DIM + 1];
    __shared__ float ld[F_DIM];
    __shared__ float dsh[F_DIM];
    __shared__ int   badsh;
    const int g = blockIdx.x;
    const int t = threadIdx.x;   // 0..255
    const float* covg = cov + (size_t)g * F_DIM * F_DIM;

    if (t == 0) badsh = 0;
    __syncthreads();

    // Coalesced 4-wave sweep: check off-diagonals, capture diagonal values.
    int bad = 0;
    const float4* cov4 = (const float4*)covg;
#pragma unroll
    for (int i = 0; i < 4; ++i) {
        const float4 v = cov4[i * 256 + t];
        const int base = (i * 256 + t) * 4;
        const float vv[4] = {v.x, v.y, v.z, v.w};
#pragma unroll
        for (int c = 0; c < 4; ++c) {
            const int flat = base + c;
            const int r = flat >> 6, col = flat & 63;
            if (r == col) dsh[r] = vv[c];
            else if (vv[c] != 0.0f) bad = 1;
        }
    }
    if (bad) badsh = 1;          // benign same-value race
    __syncthreads();
    const int anybad = badsh;
    if (t == 0) gflag[g] = anybad;

    if (!anybad) {
        // -------- diagonal fast path: coefficients only (wave 0) --------
        if (t < F_DIM) {
            const float d  = dsh[t];
            const float rs = 1.0f / sqrtf(d);
            const float m  = centers[g * F_DIM + t] * rs;
            diagv[g * F_DIM + t] = rs;
            mvec[g * F_DIM + t]  = m;
            float2 dm; dm.x = rs; dm.y = m;
            *(float2*)(cmT + (size_t)(t * G_DIM + g) * 2) = dm;  // [dim][g]

            float lg = logf(d);
#pragma unroll
            for (int off = 1; off < 64; off <<= 1) lg += __shfl_xor(lg, off);
            if (t == 0) kconst[g] = lg + (float)F_DIM * LOG2PI;
        }
        return;
    }

    // -------- general fallback: Cholesky + inverse (t<64 work) --------
    if (t < F_DIM)
        for (int j = 0; j < F_DIM; ++j) a[t][j] = covg[t * F_DIM + j];
    __syncthreads();

    for (int j = 0; j < F_DIM; ++j) {
        if (t == j) a[j][j] = sqrtf(a[j][j]);
        __syncthreads();
        if (t < F_DIM && t > j) a[t][j] /= a[j][j];
        __syncthreads();
        if (t < F_DIM && t > j) {
            const float ltj = a[t][j];
            for (int k = j + 1; k <= t; ++k) a[t][k] -= ltj * a[k][j];
        }
        __syncthreads();
    }

    if (t < F_DIM) {
        ld[t] = logf(a[t][t]);
        // thread t owns column t of Linv
        const int c = t;
        for (int i = 0; i < c; ++i) yv[i][c] = 0.0f;
        yv[c][c] = 1.0f / a[c][c];
        for (int i = c + 1; i < F_DIM; ++i) {
            float s = 0.0f;
            for (int k = c; k < i; ++k) s += a[i][k] * yv[k][c];
            yv[i][c] = -s / a[i][i];
        }
    }
    __syncthreads();

    if (t < F_DIM) {
        for (int j = 0; j < F_DIM; ++j)
            Ainv[(size_t)g * F_DIM * F_DIM + t * F_DIM + j] = yv[t][j];
        diagv[g * F_DIM + t] = yv[t][t];

        const float* cg = centers + g * F_DIM;
        float s = 0.0f;
        for (int j = 0; j <= t; ++j) s += yv[t][j] * cg[j];
        mvec[g * F_DIM + t] = s;

        if (t == 0) {
            float sum = 0.0f;
            for (int j = 0; j < F_DIM; ++j) sum += ld[j];
            kconst[g] = 2.0f * sum + (float)F_DIM * LOG2PI;
        }
    }
}

// ---------------------------------------------------------------------------
// Main, 1D grid of npts/16 blocks x 256 threads (PPW=4 -> ~4 blocks/CU TLP).
// All-diag fast path (transposed): cmT (32 KB, whole coefficient table)
//   staged into LDS once per block; lane = gaussian, per-lane registers via
//   ds_read_b64 (2-way alias = free); x rows read wave-uniformly, fully
//   unrolled 2x2-point pairing so all loads issue up front.
// Mixed/general fallback: first gridDim.x/2 blocks replicate the proven R8
//   (npts/256, 8) work split; the rest exit.
// ---------------------------------------------------------------------------
__global__ __launch_bounds__(PTS)
void gm_main(const float* __restrict__ x,
             const float* __restrict__ Ainv,
             const float* __restrict__ diagv,
             const float* __restrict__ mvec,
             const float* __restrict__ cmT,
             const float* __restrict__ kconst,
             const int* __restrict__ gflag,
             float* __restrict__ out)
{
    __shared__ union {
        float2 cmS[G_DIM * F_DIM];           // diag path: [j][g] {rs, m} 32 KB
        struct {                             // general/mixed path
            float As[F_DIM * F_DIM];
            float Ds[GPB * F_DIM];
            float Ms[GPB * F_DIM];
            float Kc[GPB];
        } gen;
    } sh;
    const int t = threadIdx.x;
    const int lane = t & 63;

    // Block-uniform: every wave's lanes 0..63 read gflag[0..63].
    const int anyoff = __any(gflag[lane] != 0);

    if (!anyoff) {
        // ---------------- transposed all-diag fast path ----------------
        // Stage the full coefficient table once per block (coalesced float4).
        {
            const float4* src = (const float4*)cmT;   // 2048 float4
            float4* dst = (float4*)sh.cmS;
#pragma unroll
            for (int r = 0; r < 8; ++r) dst[r * PTS + t] = src[r * PTS + t];
        }
        const float kg = kconst[lane];
        __syncthreads();

        // Per-lane register fill from LDS (ds_read_b64, 2-way alias -> free).
        float2 dm[F_DIM];
#pragma unroll
        for (int j = 0; j < F_DIM; ++j) dm[j] = sh.cmS[j * G_DIM + lane];

        const int w = __builtin_amdgcn_readfirstlane(t >> 6);
        const int pbase = blockIdx.x * (4 * PPW) + w * PPW;

#pragma unroll
        for (int i = 0; i < PPW; i += 2) {
            const int pa = pbase + i, pb = pbase + i + 1;
            const float4* xa = (const float4*)(x + (size_t)pa * F_DIM);
            const float4* xb = (const float4*)(x + (size_t)pb * F_DIM);
            float a0 = 0.0f, a1 = 0.0f, a2 = 0.0f, a3 = 0.0f;
            float b0 = 0.0f, b1 = 0.0f, b2 = 0.0f, b3 = 0.0f;
#pragma unroll
            for (int j4 = 0; j4 < F_DIM / 4; ++j4) {
                const float4 va = xa[j4];   // wave-uniform -> broadcast
                const float4 vb = xb[j4];
                const float2 c0 = dm[4 * j4 + 0];
                const float2 c1 = dm[4 * j4 + 1];
                const float2 c2 = dm[4 * j4 + 2];
                const float2 c3 = dm[4 * j4 + 3];
                float z;
                z = fmaf(va.x, c0.x, -c0.y); a0 = fmaf(z, z, a0);
                z = fmaf(va.y, c1.x, -c1.y); a1 = fmaf(z, z, a1);
                z = fmaf(va.z, c2.x, -c2.y); a2 = fmaf(z, z, a2);
                z = fmaf(va.w, c3.x, -c3.y); a3 = fmaf(z, z, a3);
                z = fmaf(vb.x, c0.x, -c0.y); b0 = fmaf(z, z, b0);
                z = fmaf(vb.y, c1.x, -c1.y); b1 = fmaf(z, z, b1);
                z = fmaf(vb.z, c2.x, -c2.y); b2 = fmaf(z, z, b2);
                z = fmaf(vb.w, c3.x, -c3.y); b3 = fmaf(z, z, b3);
            }
            out[(size_t)pa * G_DIM + lane] =
                __expf(-0.5f * (((a0 + a1) + (a2 + a3)) + kg));
            out[(size_t)pb * G_DIM + lane] =
                __expf(-0.5f * (((b0 + b1) + (b2 + b3)) + kg));
        }
        return;
    }

    // ---------------- mixed / general path ----------------
    // Replicates the proven (npts/256, 8) split on the first half of the grid.
    if (blockIdx.x >= (gridDim.x >> 1)) return;
    const int pblk = blockIdx.x >> 3;
    const int g0   = (blockIdx.x & 7) * GPB;
    const size_t p = (size_t)pblk * PTS + t;

    float xr[F_DIM];
    const float4* xp = (const float4*)(x + p * F_DIM);
#pragma unroll
    for (int j = 0; j < F_DIM / 4; ++j) {
        const float4 v = xp[j];
        xr[4 * j + 0] = v.x; xr[4 * j + 1] = v.y;
        xr[4 * j + 2] = v.z; xr[4 * j + 3] = v.w;
    }

    ((float2*)sh.gen.Ds)[t] = ((const float2*)(diagv + g0 * F_DIM))[t];
    ((float2*)sh.gen.Ms)[t] = ((const float2*)(mvec  + g0 * F_DIM))[t];
    if (t < GPB) sh.gen.Kc[t] = kconst[g0 + t];
    __syncthreads();

    float o[GPB];
    for (int gi = 0; gi < GPB; ++gi) {
        const int g = g0 + gi;
        float maha = 0.0f;
        if (gflag[g] == 0) {           // block-uniform branch
            const float4* dv = (const float4*)(sh.gen.Ds + gi * F_DIM);
            const float4* mv = (const float4*)(sh.gen.Ms + gi * F_DIM);
            float m0 = 0.0f, m1 = 0.0f, m2 = 0.0f, m3 = 0.0f;
#pragma unroll
            for (int j = 0; j < F_DIM / 4; ++j) {
                const float4 d = dv[j];
                const float4 m = mv[j];
                const float z0 = fmaf(xr[4 * j + 0], d.x, -m.x);
                const float z1 = fmaf(xr[4 * j + 1], d.y, -m.y);
                const float z2 = fmaf(xr[4 * j + 2], d.z, -m.z);
                const float z3 = fmaf(xr[4 * j + 3], d.w, -m.w);
                m0 = fmaf(z0, z0, m0);
                m1 = fmaf(z1, z1, m1);
                m2 = fmaf(z2, z2, m2);
                m3 = fmaf(z3, z3, m3);
            }
            maha = (m0 + m1) + (m2 + m3);
        } else {
            __syncthreads();   // As reuse (uniform: gflag same blockwide)
            const float4* Ag = (const float4*)(Ainv + (size_t)g * F_DIM * F_DIM);
            float4* As4 = (float4*)sh.gen.As;
#pragma unroll
            for (int r = 0; r < 4; ++r) As4[r * PTS + t] = Ag[r * PTS + t];
            __syncthreads();
#pragma unroll 8
            for (int i = 0; i < F_DIM; ++i) {
                const float4* row = (const float4*)(sh.gen.As + i * F_DIM);
                float a0 = 0.0f, a1 = 0.0f, a2 = 0.0f, a3 = 0.0f;
#pragma unroll
                for (int j = 0; j < F_DIM / 4; ++j) {
                    const float4 v = row[j];
                    a0 = fmaf(v.x, xr[4 * j + 0], a0);
                    a1 = fmaf(v.y, xr[4 * j + 1], a1);
                    a2 = fmaf(v.z, xr[4 * j + 2], a2);
                    a3 = fmaf(v.w, xr[4 * j + 3], a3);
                }
                const float z = ((a0 + a2) + (a1 + a3)) - sh.gen.Ms[gi * F_DIM + i];
                maha = fmaf(z, z, maha);
            }
        }
        o[gi] = __expf(-0.5f * (maha + sh.gen.Kc[gi]));
    }
#pragma unroll
    for (int gi = 0; gi < GPB; ++gi) out[p * G_DIM + g0 + gi] = o[gi];
}

// ---------------------------------------------------------------------------
extern "C" void kernel_launch(void* const* d_in, const int* in_sizes, int n_in,
                              void* d_out, int out_size, void* d_ws, size_t ws_size,
                              hipStream_t stream) {
    const float* x       = (const float*)d_in[0];
    const float* centers = (const float*)d_in[1];
    const float* cov     = (const float*)d_in[2];
    float* out = (float*)d_out;

    char* ws = (char*)d_ws;
    const size_t ainv_bytes = (size_t)G_DIM * F_DIM * F_DIM * sizeof(float); // 1 MiB
    const size_t gf_bytes   = (size_t)G_DIM * F_DIM * sizeof(float);         // 16 KiB
    float* Ainv   = (float*)(ws);
    float* mvec   = (float*)(ws + ainv_bytes);
    float* kconst = (float*)(ws + ainv_bytes + gf_bytes);
    float* diagv  = (float*)(ws + ainv_bytes + gf_bytes + 1024);
    int*   gflag  = (int*)  (ws + ainv_bytes + gf_bytes + 1024 + gf_bytes);
    float* cmT    = (float*)(ws + ainv_bytes + gf_bytes + 1024 + gf_bytes + 1024);

    const int npts = in_sizes[0] / F_DIM;   // 16384

    gm_setup<<<G_DIM, 256, 0, stream>>>(centers, cov, Ainv, diagv, mvec,
                                        cmT, kconst, gflag);

    gm_main<<<npts / (4 * PPW), PTS, 0, stream>>>(x, Ainv, diagv, mvec, cmT,
                                                  kconst, gflag, out);
}